// Round 3
// baseline (748.918 us; speedup 1.0000x reference)
//
#include <hip/hip_runtime.h>

#define DI __device__ __forceinline__

typedef float f32x4 __attribute__((ext_vector_type(4)));
typedef short s16x8 __attribute__((ext_vector_type(8)));

constexpr int N_ = 64, T_ = 300, V_ = 25, C_ = 64, K_ = 3, F_ = 64, I_ = 16;

// round-to-nearest-even f32 -> bf16 (as raw short) — scalar path
DI short f2bf(float f) {
  union { float f; unsigned u; } v; v.f = f;
  unsigned r = (v.u + 0x7fffu + ((v.u >> 16) & 1u)) >> 16;
  return (short)r;
}

// pack two f32 -> two bf16 in one u32 (round-half-up via +0x8000, then v_perm)
DI unsigned pk2bf(float a, float b) {
  union { float f; unsigned u; } x, y; x.f = a; y.f = b;
  return __builtin_amdgcn_perm(y.u + 0x8000u, x.u + 0x8000u, 0x07060302u);
}

DI void gload_lds16(const void* g, void* l) {
  __builtin_amdgcn_global_load_lds(
      (const __attribute__((address_space(1))) unsigned*)g,
      (__attribute__((address_space(3))) unsigned*)l, 16, 0, 0);
}

// ===========================================================================
// NEW PATH
// ===========================================================================

// k0: x (f32) -> xbf: [n][t][32 v-pad][64 c] bf16, cols XOR-swizzled c^((v&7)<<3),
//     pad rows zero.  Blocks 0..7 additionally prep wqk[96][64] / wm[192][64]
//     (transposed bf16 weight tables, linear layout).
__global__ __launch_bounds__(256) void k0_prep(
    const float* __restrict__ x, const float* __restrict__ Wq,
    const float* __restrict__ Wk, const float* __restrict__ W,
    unsigned short* __restrict__ xbf, unsigned short* __restrict__ wqk,
    unsigned short* __restrict__ wm)
{
  const int tid = threadIdx.x, lane = tid & 63, wid = tid >> 6;

  if (blockIdx.x < 8) {
    for (int idx = blockIdx.x * 256 + tid; idx < 96 * 64; idx += 2048) {
      int j = idx >> 6, c = idx & 63;
      float v = (j < 48) ? Wq[(j >> 4) * (C_ * I_) + c * I_ + (j & 15)]
                         : Wk[((j - 48) >> 4) * (C_ * I_) + c * I_ + ((j - 48) & 15)];
      wqk[idx] = (unsigned short)f2bf(v);
    }
    for (int idx = blockIdx.x * 256 + tid; idx < 192 * 64; idx += 2048) {
      int kc = idx >> 6, c = idx & 63;
      wm[idx] = (unsigned short)f2bf(W[c * 192 + kc]);
    }
  }

  int row = blockIdx.x * 4 + wid;  // (n,t) row id 0..19199
  if (row < N_ * T_) {
    const float* xr = x + (size_t)row * (V_ * C_);
    unsigned short* outr = xbf + (size_t)row * (32 * 64);
#pragma unroll
    for (int w = 0; w < 8; ++w) {
      int o = lane * 4 + w * 256;          // short index in 32*64 tile
      int v = o >> 6, cs = o & 63;
      int c0 = cs ^ ((v & 7) << 3);        // mult of 4 (XOR hits bits 3-5)
      uint2 val; val.x = 0u; val.y = 0u;
      if (v < 25) {
        f32x4 f = *(const f32x4*)(xr + v * 64 + c0);
        val.x = pk2bf(f[0], f[1]); val.y = pk2bf(f[2], f[3]);
      }
      *(uint2*)(outr + o) = val;
    }
  }
}

// k1: grid (G,64). Block (p,n) processes chunks [p*nChunks, min(..,75)) of 4 t's.
//     P-stage (operand-swapped): D[j][tv] -> b64 writes into P[tv][104].
//     S-stage accumulates q.k^T in registers; store partials to Spart.
__global__ __launch_bounds__(256, 3) void k1_scores(
    const unsigned short* __restrict__ xbf, const unsigned short* __restrict__ wqk,
    const float* __restrict__ bq, const float* __restrict__ bk,
    float* __restrict__ Spart, int nChunks)
{
  __shared__ __align__(16) unsigned short Xl[128 * 64];   // 16 KB
  __shared__ __align__(16) unsigned short P[128 * 104];   // 26.6 KB  [tv][j:96 pad104]

  const int tid = threadIdx.x, lane = tid & 63, wid = tid >> 6;
  const int g = lane >> 4, lo = lane & 15;
  const int n = blockIdx.y, p = blockIdx.x;
  const int c0 = p * nChunks;
  const int c1 = (c0 + nChunks < 75) ? c0 + nChunks : 75;

  // preload W fragments (A-operand: row=j=mj*16+lo, k-elems ks*32+g*8..+7)
  s16x8 wf[12];
#pragma unroll
  for (int mj = 0; mj < 6; ++mj)
#pragma unroll
    for (int ks = 0; ks < 2; ++ks)
      wf[mj * 2 + ks] = *(const s16x8*)(wqk + (mj * 16 + lo) * 64 + ks * 32 + g * 8);

  f32x4 bias4[6];
#pragma unroll
  for (int mj = 0; mj < 6; ++mj) {
    const float* bp = (mj < 3) ? (bq + mj * 16 + g * 4) : (bk + (mj - 3) * 16 + g * 4);
    bias4[mj] = *(const f32x4*)bp;
  }

  f32x4 acc[3];
#pragma unroll
  for (int j = 0; j < 3; ++j) acc[j] = (f32x4){0.f, 0.f, 0.f, 0.f};

  // stage helper: 16 KB contiguous (layout matches xbf exactly)
  const size_t nbase = (size_t)n * T_ * 2048;  // shorts
  if (c0 < c1) {
    const char* src = (const char*)(xbf + nbase + (size_t)c0 * 4 * 2048);
#pragma unroll
    for (int it = 0; it < 4; ++it)
      gload_lds16(src + it * 4096 + wid * 1024 + lane * 16,
                  (char*)Xl + it * 4096 + wid * 1024);
  }
  __syncthreads();

  for (int ch = c0; ch < c1; ++ch) {
    // P-stage: 48 tiles (6 mj x 8 ntv), 2 MFMA each
#pragma unroll
    for (int i = 0; i < 12; ++i) {
      int tile = wid + i * 4;
      int mj = tile >> 3, ntv = tile & 7;
      f32x4 pa = bias4[mj];
      int tv = ntv * 16 + lo;
#pragma unroll
      for (int ks = 0; ks < 2; ++ks) {
        s16x8 bfrag = *(const s16x8*)&Xl[tv * 64 + ((ks * 32 + g * 8) ^ ((tv & 7) << 3))];
        pa = __builtin_amdgcn_mfma_f32_16x16x32_bf16(wf[mj * 2 + ks], bfrag, pa, 0, 0, 0);
      }
      int jb = mj * 16 + g * 4;
      uint2 w2; w2.x = pk2bf(pa[0], pa[1]); w2.y = pk2bf(pa[2], pa[3]);
      *(uint2*)&P[tv * 104 + jb] = w2;
    }
    __syncthreads();

    // async prefetch next chunk's Xl while S-stage reads only P
    if (ch + 1 < c1) {
      const char* src = (const char*)(xbf + nbase + (size_t)(ch + 1) * 4 * 2048);
#pragma unroll
      for (int it = 0; it < 4; ++it)
        gload_lds16(src + it * 4096 + wid * 1024 + lane * 16,
                    (char*)Xl + it * 4096 + wid * 1024);
    }

    // S-stage: 12 combos (k, vt, wt), 3 per wave
#pragma unroll
    for (int j = 0; j < 3; ++j) {
      int combo = wid + j * 4;
      int k = combo >> 2, vt = (combo >> 1) & 1, wt = combo & 1;
#pragma unroll
      for (int ks = 0; ks < 2; ++ks) {
        int t = ks * 2 + (g >> 1), ib = (g & 1) * 8;
        int v = vt * 16 + lo, w = wt * 16 + lo;
        s16x8 aq = *(const s16x8*)&P[(t * 32 + v) * 104 + k * 16 + ib];
        s16x8 bk2 = *(const s16x8*)&P[(t * 32 + w) * 104 + 48 + k * 16 + ib];
        acc[j] = __builtin_amdgcn_mfma_f32_16x16x32_bf16(aq, bk2, acc[j], 0, 0, 0);
      }
    }
    __syncthreads();
  }

#pragma unroll
  for (int j = 0; j < 3; ++j) {
    int combo = wid + j * 4;
    int k = combo >> 2, vt = (combo >> 1) & 1, wt = combo & 1;
#pragma unroll
    for (int r = 0; r < 4; ++r) {
      int v = vt * 16 + g * 4 + r;
      int w = wt * 16 + lo;
      if (v < 25 && w < 25)
        Spart[((size_t)p * 192 + (k * 64 + n)) * 625 + v * 25 + w] = acc[j][r];
    }
  }
}

// k2: reduce partials over p, softmax + A -> aad [k*64+n][32 w][40 v] bf16, pads zero
__global__ void k2_softmax(const float* __restrict__ Spart,
                           const float* __restrict__ A,
                           unsigned short* __restrict__ aad, int G)
{
  __shared__ float Ss[625];
  int bx = blockIdx.x, k = bx >> 6, tid = threadIdx.x;
  unsigned short* outb = aad + (size_t)bx * 1280;
  for (int idx = tid; idx < 640; idx += 256) ((unsigned*)outb)[idx] = 0u;
  for (int cell = tid; cell < 625; cell += 256) {
    float s = 0.f;
    for (int pp = 0; pp < G; ++pp)
      s += Spart[((size_t)pp * 192 + bx) * 625 + cell];
    Ss[cell] = s;
  }
  __syncthreads();
  if (tid < 25) {
    int v = tid;
    const float scale = 0.014433756729740645f;  // 1/sqrt(4800)
    float s[25];
    float mx = -1e30f;
#pragma unroll
    for (int w = 0; w < 25; ++w) { s[w] = Ss[v * 25 + w] * scale; mx = fmaxf(mx, s[w]); }
    float sum = 0.f;
#pragma unroll
    for (int w = 0; w < 25; ++w) { s[w] = __expf(s[w] - mx); sum += s[w]; }
    float inv = 1.f / sum;
#pragma unroll
    for (int w = 0; w < 25; ++w) {
      float aadv = A[(k * 25 + v) * 25 + w] + s[w] * inv;
      outb[w * 40 + v] = (unsigned short)f2bf(aadv);
    }
  }
}

// k3: grid (75,64): block = (4 t's, n). Stage Xl (gload_lds) + Al.
//     For k=0..2: h-stage (Xl x wm-frags -> Ht[64][136], b64 writes);
//     agg MFMA accumulating y in regs across k. Store y.
__global__ __launch_bounds__(256, 3) void k3_main(
    const unsigned short* __restrict__ xbf, const unsigned short* __restrict__ wm,
    const float* __restrict__ b_, const unsigned short* __restrict__ aad,
    float* __restrict__ y)
{
  __shared__ __align__(16) unsigned short Xl[128 * 64];   // 16 KB
  __shared__ __align__(16) unsigned short Ht[64 * 136];   // 17 KB [kc_local][tv:128 pad136]
  __shared__ __align__(16) unsigned short Al[3 * 32 * 40];// 7.7 KB [k][w][v pad40]

  const int tid = threadIdx.x, lane = tid & 63, wid = tid >> 6;
  const int g = lane >> 4, lo = lane & 15;
  const int n = blockIdx.y, t0 = blockIdx.x * 4;

  {
    const char* src = (const char*)(xbf + ((size_t)n * T_ + t0) * 2048);
#pragma unroll
    for (int it = 0; it < 4; ++it)
      gload_lds16(src + it * 4096 + wid * 1024 + lane * 16,
                  (char*)Xl + it * 4096 + wid * 1024);
  }
  // Al: 3 pieces of 2560 B (16B-vector copy)
  for (int idx = tid; idx < 480; idx += 256) {
    int k = idx / 160, rem = idx - k * 160;
    s16x8 v = *(const s16x8*)(aad + ((size_t)(k * 64 + n)) * 1280 + rem * 8);
    *(s16x8*)&Al[k * 1280 + rem * 8] = v;
  }
  __syncthreads();

  f32x4 acc[8];
#pragma unroll
  for (int i = 0; i < 8; ++i) acc[i] = (f32x4){0.f, 0.f, 0.f, 0.f};

  for (int k = 0; k < 3; ++k) {
    // W frags (B-operand: row=kc=nt*16+lo) + biases
    s16x8 wf[8];
    float bz[4];
#pragma unroll
    for (int nt = 0; nt < 4; ++nt) {
      bz[nt] = b_[k * 64 + nt * 16 + lo];
#pragma unroll
      for (int ks = 0; ks < 2; ++ks)
        wf[nt * 2 + ks] = *(const s16x8*)(wm + (k * 64 + nt * 16 + lo) * 64 + ks * 32 + g * 8);
    }

    // h-stage: 32 tiles (8 m x 4 nt)
#pragma unroll
    for (int i = 0; i < 8; ++i) {
      int tile = wid + i * 4;
      int m = tile >> 2, nt = tile & 3;
      f32x4 ha = (f32x4){bz[nt], bz[nt], bz[nt], bz[nt]};
      int tv = m * 16 + lo;
#pragma unroll
      for (int ks = 0; ks < 2; ++ks) {
        s16x8 af = *(const s16x8*)&Xl[tv * 64 + ((ks * 32 + g * 8) ^ ((tv & 7) << 3))];
        ha = __builtin_amdgcn_mfma_f32_16x16x32_bf16(af, wf[nt * 2 + ks], ha, 0, 0, 0);
      }
      int kcl = nt * 16 + lo, tvb = m * 16 + g * 4;
      uint2 w2; w2.x = pk2bf(ha[0], ha[1]); w2.y = pk2bf(ha[2], ha[3]);
      *(uint2*)&Ht[kcl * 136 + tvb] = w2;
    }
    __syncthreads();

    // agg: 32 jobs (t, wt, ct), 8 per wave, K=32 over v
#pragma unroll
    for (int i = 0; i < 8; ++i) {
      int job = wid + i * 4;
      int t = job >> 3, rem = job & 7, wt = rem >> 2, ct = rem & 3;
      s16x8 af = *(const s16x8*)&Al[(k * 32 + wt * 16 + lo) * 40 + g * 8];
      s16x8 bf_ = *(const s16x8*)&Ht[(ct * 16 + lo) * 136 + t * 32 + g * 8];
      acc[i] = __builtin_amdgcn_mfma_f32_16x16x32_bf16(af, bf_, acc[i], 0, 0, 0);
    }
    __syncthreads();
  }

#pragma unroll
  for (int i = 0; i < 8; ++i) {
    int job = wid + i * 4;
    int t = job >> 3, rem = job & 7, wt = rem >> 2, ct = rem & 3;
#pragma unroll
    for (int r = 0; r < 4; ++r) {
      int w = wt * 16 + g * 4 + r;
      if (w < 25)
        y[(((size_t)n * T_ + t0 + t) * V_ + w) * C_ + ct * 16 + lo] = acc[i][r];
    }
  }
}

// ===========================================================================
// FALLBACK PATH (R2, known-good) — used if ws_size too small for xbf plan
// ===========================================================================
__global__ __launch_bounds__(256, 2) void k1_fb(
    const float* __restrict__ x,
    const float* __restrict__ Wq, const float* __restrict__ bq,
    const float* __restrict__ Wk, const float* __restrict__ bk,
    float* __restrict__ Spart, int nChunks)
{
  __shared__ __align__(16) short Xl[112 * 64];
  __shared__ __align__(16) short Wt[96 * 64];
  __shared__ __align__(16) short Pq[4 * 32 * 64];
  __shared__ __align__(16) short Pk[4 * 32 * 64];
  __shared__ float bcl[96];
  const int tid = threadIdx.x, lane = tid & 63, wid = tid >> 6;
  const int g = lane >> 4, lo = lane & 15;
  const int n = blockIdx.y, p = blockIdx.x;
  for (int idx = tid; idx < 96 * 64; idx += 256) {
    int j = idx >> 6, c = idx & 63;
    float v;
    if (j < 48) v = Wq[(j >> 4) * (C_ * I_) + c * I_ + (j & 15)];
    else { int j2 = j - 48; v = Wk[(j2 >> 4) * (C_ * I_) + c * I_ + (j2 & 15)]; }
    Wt[j * 64 + (c ^ ((j & 7) << 3))] = f2bf(v);
  }
  if (tid < 96) bcl[tid] = (tid < 48) ? bq[tid] : bk[tid - 48];
  f32x4 acc[3];
#pragma unroll
  for (int j = 0; j < 3; ++j) acc[j] = (f32x4){0.f, 0.f, 0.f, 0.f};
  for (int chunk = 0; chunk < nChunks; ++chunk) {
    const int t0row = (p * nChunks + chunk) * 100;
    {
      const float* xb = x + (size_t)n * (T_ * V_ * C_) + (size_t)t0row * C_;
      for (int idx = tid; idx < 112 * 64; idx += 256) {
        int row = idx >> 6, c = idx & 63;
        float v = (row < 100) ? xb[idx] : 0.f;
        Xl[row * 64 + (c ^ ((row & 7) << 3))] = f2bf(v);
      }
    }
    __syncthreads();
    for (int i = 0; i < 11; ++i) {
      int tile = wid + i * 4;
      if (tile >= 42) break;
      int m = tile / 6, nt = tile % 6;
      float binit = bcl[nt * 16 + lo];
      f32x4 pacc = { binit, binit, binit, binit };
#pragma unroll
      for (int ks = 0; ks < 2; ++ks) {
        int arow = m * 16 + lo;
        s16x8 a = *(const s16x8*)&Xl[arow * 64 + ((ks * 32 + g * 8) ^ ((arow & 7) << 3))];
        int brow = nt * 16 + lo;
        s16x8 b = *(const s16x8*)&Wt[brow * 64 + ((ks * 32 + g * 8) ^ ((brow & 7) << 3))];
        pacc = __builtin_amdgcn_mfma_f32_16x16x32_bf16(a, b, pacc, 0, 0, 0);
      }
#pragma unroll
      for (int r = 0; r < 4; ++r) {
        int row = m * 16 + g * 4 + r;
        if (row < 100) {
          int t = row / 25, v = row - t * 25;
          int j = nt * 16 + lo;
          short val = f2bf(pacc[r]);
          if (j < 48) Pq[(t * 32 + v) * 64 + (j ^ ((v & 7) << 3))] = val;
          else        Pk[(t * 32 + v) * 64 + ((j - 48) ^ ((v & 7) << 3))] = val;
        }
      }
    }
    __syncthreads();
#pragma unroll
    for (int j = 0; j < 3; ++j) {
      int combo = wid + j * 4;
      int k = combo >> 2, vt = (combo >> 1) & 1, wt = combo & 1;
#pragma unroll
      for (int ks = 0; ks < 2; ++ks) {
        int t = ks * 2 + (g >> 1);
        int ib = (g & 1) * 8;
        int v = vt * 16 + lo;
        s16x8 a = *(const s16x8*)&Pq[(t * 32 + v) * 64 + ((k * 16 + ib) ^ ((v & 7) << 3))];
        int w = wt * 16 + lo;
        s16x8 b = *(const s16x8*)&Pk[(t * 32 + w) * 64 + ((k * 16 + ib) ^ ((w & 7) << 3))];
        acc[j] = __builtin_amdgcn_mfma_f32_16x16x32_bf16(a, b, acc[j], 0, 0, 0);
      }
    }
    __syncthreads();
  }
#pragma unroll
  for (int j = 0; j < 3; ++j) {
    int combo = wid + j * 4;
    int k = combo >> 2, vt = (combo >> 1) & 1, wt = combo & 1;
#pragma unroll
    for (int r = 0; r < 4; ++r) {
      int v = vt * 16 + g * 4 + r;
      int w = wt * 16 + lo;
      if (v < 25 && w < 25)
        Spart[((size_t)p * 192 + (k * 64 + n)) * 625 + v * 25 + w] = acc[j][r];
    }
  }
}

__global__ void k2_fb(const float* __restrict__ Spart, const float* __restrict__ A,
                      unsigned short* __restrict__ AadT, int G)
{
  __shared__ float Ss[625];
  int bx = blockIdx.x, k = bx >> 6, tid = threadIdx.x;
  unsigned short* outb = AadT + (size_t)bx * 1024;
  for (int idx = tid; idx < 1024; idx += 256) outb[idx] = 0;
  for (int cell = tid; cell < 625; cell += 256) {
    float s = 0.f;
    for (int pp = 0; pp < G; ++pp) s += Spart[((size_t)pp * 192 + bx) * 625 + cell];
    Ss[cell] = s;
  }
  __syncthreads();
  if (tid < 25) {
    int v = tid;
    const float scale = 0.014433756729740645f;
    float s[25];
    float mx = -1e30f;
#pragma unroll
    for (int w = 0; w < 25; ++w) { s[w] = Ss[v * 25 + w] * scale; mx = fmaxf(mx, s[w]); }
    float sum = 0.f;
#pragma unroll
    for (int w = 0; w < 25; ++w) { s[w] = __expf(s[w] - mx); sum += s[w]; }
    float inv = 1.f / sum;
#pragma unroll
    for (int w = 0; w < 25; ++w) {
      float aad = A[(k * 25 + v) * 25 + w] + s[w] * inv;
      outb[w * 32 + v] = (unsigned short)f2bf(aad);
    }
  }
}

__global__ __launch_bounds__(256, 2) void k3_fb(
    const float* __restrict__ x,
    const float* __restrict__ W, const float* __restrict__ b,
    const unsigned short* __restrict__ AadT, float* __restrict__ y)
{
  __shared__ __align__(16) short Xl[80 * 64];
  __shared__ __align__(16) short Wt[192 * 64];
  __shared__ __align__(16) short Ht[192 * 96];
  __shared__ __align__(16) short Al[3 * 32 * 32];
  __shared__ float bl[192];
  const int tid = threadIdx.x, lane = tid & 63, wid = tid >> 6;
  const int g = lane >> 4, lo = lane & 15;
  const int n = blockIdx.y, t0 = blockIdx.x * 3;
  for (int idx = tid; idx < 192 * 64; idx += 256) {
    int c = idx / 192, j = idx % 192;
    Wt[j * 64 + (c ^ ((j & 7) << 3))] = f2bf(W[idx]);
  }
  if (tid < 192) bl[tid] = b[tid];
  for (int idx = tid; idx < 3 * 1024; idx += 256) {
    int kk = idx >> 10, rem = idx & 1023, w = rem >> 5, v = rem & 31;
    unsigned short val = AadT[(size_t)(kk * 64 + n) * 1024 + rem];
    Al[(kk * 32 + w) * 32 + (v ^ ((w & 3) << 3))] = (short)val;
  }
  for (int idx = tid; idx < 192 * 24; idx += 256) {
    int kc = idx / 24, rem = idx % 24, t = rem >> 3, vv = 24 + (rem & 7);
    Ht[kc * 96 + ((t * 32 + vv) ^ ((kc & 3) << 3))] = 0;
  }
  {
    const float* xb = x + (size_t)n * (T_ * V_ * C_) + (size_t)t0 * (V_ * C_);
    for (int idx = tid; idx < 80 * 64; idx += 256) {
      int row = idx >> 6, c = idx & 63;
      float v = (row < 75) ? xb[idx] : 0.f;
      Xl[row * 64 + (c ^ ((row & 7) << 3))] = f2bf(v);
    }
  }
  __syncthreads();
#pragma unroll
  for (int i = 0; i < 15; ++i) {
    int tile = wid + i * 4;
    int m = tile / 12, nt = tile % 12;
    float binit = bl[nt * 16 + lo];
    f32x4 acc = { binit, binit, binit, binit };
#pragma unroll
    for (int ks = 0; ks < 2; ++ks) {
      int arow = m * 16 + lo;
      s16x8 a = *(const s16x8*)&Xl[arow * 64 + ((ks * 32 + g * 8) ^ ((arow & 7) << 3))];
      int brow = nt * 16 + lo;
      s16x8 bb = *(const s16x8*)&Wt[brow * 64 + ((ks * 32 + g * 8) ^ ((brow & 7) << 3))];
      acc = __builtin_amdgcn_mfma_f32_16x16x32_bf16(a, bb, acc, 0, 0, 0);
    }
#pragma unroll
    for (int r = 0; r < 4; ++r) {
      int row = m * 16 + g * 4 + r;
      if (row < 75) {
        int t = row / 25, v = row - t * 25;
        int kc = nt * 16 + lo;
        Ht[kc * 96 + ((t * 32 + v) ^ ((kc & 3) << 3))] = f2bf(acc[r]);
      }
    }
  }
  __syncthreads();
#pragma unroll
  for (int i = 0; i < 6; ++i) {
    int job = wid + i * 4;
    int t = job >> 3, rem = job & 7, wt = rem >> 2, ct = rem & 3;
    f32x4 acc = { 0.f, 0.f, 0.f, 0.f };
#pragma unroll
    for (int k3 = 0; k3 < 3; ++k3) {
      int w = wt * 16 + lo;
      s16x8 a = *(const s16x8*)&Al[(k3 * 32 + w) * 32 + ((g * 8) ^ ((w & 3) << 3))];
      int kc = k3 * 64 + ct * 16 + lo;
      s16x8 bb = *(const s16x8*)&Ht[kc * 96 + ((t * 32 + g * 8) ^ ((kc & 3) << 3))];
      acc = __builtin_amdgcn_mfma_f32_16x16x32_bf16(a, bb, acc, 0, 0, 0);
    }
#pragma unroll
    for (int r = 0; r < 4; ++r) {
      int w = wt * 16 + g * 4 + r;
      if (w < 25)
        y[(((size_t)n * T_ + t0 + t) * V_ + w) * C_ + ct * 16 + lo] = acc[r];
    }
  }
}

// ===========================================================================
extern "C" void kernel_launch(void* const* d_in, const int* in_sizes, int n_in,
                              void* d_out, int out_size, void* d_ws, size_t ws_size,
                              hipStream_t stream) {
  const float* x  = (const float*)d_in[0];
  const float* A  = (const float*)d_in[1];
  const float* W  = (const float*)d_in[2];
  const float* b  = (const float*)d_in[3];
  const float* Wq = (const float*)d_in[4];
  const float* bq = (const float*)d_in[5];
  const float* Wk = (const float*)d_in[6];
  const float* bk = (const float*)d_in[7];
  float* y = (float*)d_out;

  // new-path ws layout
  const size_t xbf_off = 0;
  const size_t xbf_sz  = (size_t)N_ * T_ * 32 * 64 * 2;        // 78,643,200
  const size_t wqk_off = xbf_off + xbf_sz;                     // 12,288
  const size_t wm_off  = wqk_off + 96 * 64 * 2;                // 24,576
  const size_t aad_off = wm_off + 192 * 64 * 2;                // 491,520
  const size_t sp_off  = aad_off + (size_t)192 * 32 * 40 * 2;
  const size_t perG    = (size_t)192 * 625 * sizeof(float);    // 480,000

  if (ws_size >= sp_off + perG) {
    unsigned short* xbf = (unsigned short*)((char*)d_ws + xbf_off);
    unsigned short* wqk = (unsigned short*)((char*)d_ws + wqk_off);
    unsigned short* wm  = (unsigned short*)((char*)d_ws + wm_off);
    unsigned short* aad = (unsigned short*)((char*)d_ws + aad_off);
    float* Spart = (float*)((char*)d_ws + sp_off);

    int G = (int)((ws_size - sp_off) / perG);
    if (G > 12) G = 12;
    int nChunks = (75 + G - 1) / G;

    k0_prep<<<dim3(4800), 256, 0, stream>>>(x, Wq, Wk, W, xbf, wqk, wm);
    k1_scores<<<dim3(G, 64), 256, 0, stream>>>(xbf, wqk, bq, bk, Spart, nChunks);
    k2_softmax<<<dim3(192), 256, 0, stream>>>(Spart, A, aad, G);
    k3_main<<<dim3(75, 64), 256, 0, stream>>>(xbf, wm, b, aad, y);
  } else {
    unsigned short* AadT = (unsigned short*)d_ws;
    float* Spart = (float*)((char*)d_ws + 512 * 1024);
    const size_t base = 512 * 1024;
    int G = 25;
    if (base + 25 * perG > ws_size) G = 15;
    if (base + 15 * perG > ws_size) G = 5;
    int nChunks = 75 / G;
    k1_fb<<<dim3(G, 64), 256, 0, stream>>>(x, Wq, bq, Wk, bk, Spart, nChunks);
    k2_fb<<<dim3(192), 256, 0, stream>>>(Spart, A, AadT, G);
    k3_fb<<<dim3(100, 64), 256, 0, stream>>>(x, W, b, AadT, y);
  }
}